// Round 1
// 267.603 us; speedup vs baseline: 1.0139x; 1.0139x over previous
//
#include <hip/hip_runtime.h>
#include <hip/hip_bf16.h>
#include <math.h>

#define BB   2
#define HWl  1024
#define DINO 768
#define COG  1920
#define NHh  12
#define TKV  4096
#define MQ   (BB*HWl)      // 2048
#define MKV  (BB*TKV)      // 8192
#define NSPL 4
#define ROWS_PER_SPLIT (BB*NHh*HWl)   // 24576

typedef __attribute__((ext_vector_type(8))) short bf16x8;
typedef __attribute__((ext_vector_type(4))) float f32x4;

__device__ __forceinline__ unsigned short f2bf_bits(float f) {
    __hip_bfloat16 h = __float2bfloat16(f);
    return *reinterpret_cast<unsigned short*>(&h);
}

__device__ __forceinline__ void glds16(const __hip_bfloat16* g, __hip_bfloat16* l) {
    __builtin_amdgcn_global_load_lds((const __attribute__((address_space(1))) void*)g,
                                     (__attribute__((address_space(3))) void*)l, 16, 0, 0);
}

// =================== prep1 mega-kernel ===================
// blocks [0,2048)     : LN of cog -> xkv bf16 (wave per row, 4 rows/block)
// blocks [2048,2432)  : dino NCHW -> xqT fp32 transpose (64x64 LDS tiles, coalesced)
// blocks [2432,8192)  : weight transposes -> WqT, WkvT(concat), WoT
__global__ __launch_bounds__(256) void prep1(const float* __restrict__ dino,
                                             const float* __restrict__ cog,
                                             const float* __restrict__ gkv, const float* __restrict__ Bkv,
                                             const float* __restrict__ Wq, const float* __restrict__ Wk,
                                             const float* __restrict__ Wv, const float* __restrict__ Wo,
                                             float* __restrict__ xqT,
                                             __hip_bfloat16* __restrict__ xkv,
                                             __hip_bfloat16* WqT, __hip_bfloat16* WkvT, __hip_bfloat16* WoT) {
    int bid = blockIdx.x, tid = threadIdx.x;
    if (bid < 2048) {
        const int W = COG, W4 = W >> 2, NC = 8;
        int row = bid * 4 + (tid >> 6), lane = tid & 63;
        const float4* xr = (const float4*)(cog + (size_t)row * W);
        const float4* g4 = (const float4*)gkv;
        const float4* b4 = (const float4*)Bkv;
        float4 v[NC];
        float s = 0.f, ss = 0.f;
        #pragma unroll
        for (int i = 0; i < NC; ++i) {
            int c = lane + i * 64;
            float4 t = (c < W4) ? xr[c] : (float4){0.f, 0.f, 0.f, 0.f};
            v[i] = t;
            s  += t.x + t.y + t.z + t.w;
            ss += t.x * t.x + t.y * t.y + t.z * t.z + t.w * t.w;
        }
        #pragma unroll
        for (int off = 1; off < 64; off <<= 1) {
            s  += __shfl_xor(s, off);
            ss += __shfl_xor(ss, off);
        }
        float mu = s / W;
        float rstd = rsqrtf(ss / W - mu * mu + 1e-5f);
        ushort4* yr = (ushort4*)(xkv + (size_t)row * W);
        #pragma unroll
        for (int i = 0; i < NC; ++i) {
            int c = lane + i * 64;
            if (c < W4) {
                float4 t = v[i];
                float4 gg = g4[c], bb = b4[c];
                ushort4 o;
                o.x = f2bf_bits((t.x - mu) * rstd * gg.x + bb.x);
                o.y = f2bf_bits((t.y - mu) * rstd * gg.y + bb.y);
                o.z = f2bf_bits((t.z - mu) * rstd * gg.z + bb.z);
                o.w = f2bf_bits((t.w - mu) * rstd * gg.w + bb.w);
                yr[c] = o;
            }
        }
    } else if (bid < 2432) {
        int t = bid - 2048;                 // 384 = 16 x 12 x 2
        int h0 = (t & 15) * 64;
        int c0 = ((t >> 4) % 12) * 64;
        int b = t / 192;
        __shared__ float T[64][65];
        #pragma unroll
        for (int i = 0; i < 16; ++i) {
            int idx = tid + i * 256;
            int c = idx >> 6, h = idx & 63;
            T[c][h] = dino[((size_t)b * DINO + c0 + c) * HWl + h0 + h];
        }
        __syncthreads();
        #pragma unroll
        for (int i = 0; i < 16; ++i) {
            int idx = tid + i * 256;
            int r = idx >> 6, c = idx & 63;
            xqT[((size_t)b * HWl + h0 + r) * DINO + c0 + c] = T[c][r];
        }
    } else {
        int bid2 = bid - 2432;
        int mid = bid2 / 1440, r = bid2 % 1440;
        int k0 = (r % 60) * 32, n0 = (r / 60) * 32;
        const float* src = (mid == 0) ? Wq : (mid == 1) ? Wk : (mid == 2) ? Wv : Wo;
        __hip_bfloat16* dst;
        int rowoff = 0;
        if (mid == 0) dst = WqT;
        else if (mid == 1) dst = WkvT;
        else if (mid == 2) { dst = WkvT; rowoff = 768; }
        else dst = WoT;
        int K = (mid == 1 || mid == 2) ? COG : DINO;
        if (k0 >= K) return;
        __shared__ float T[32][33];
        #pragma unroll
        for (int i = 0; i < 4; ++i) {
            int idx = tid + i * 256;
            int rr = idx >> 5, c = idx & 31;
            T[rr][c] = src[(size_t)(k0 + rr) * DINO + n0 + c];
        }
        __syncthreads();
        #pragma unroll
        for (int i = 0; i < 4; ++i) {
            int idx = tid + i * 256;
            int rr = idx >> 5, c = idx & 31;
            dst[(size_t)(rowoff + n0 + rr) * K + k0 + c] = __float2bfloat16(T[c][rr]);
        }
    }
}

// =================== prep2: LN of xqT rows -> xq bf16 ===================
__global__ __launch_bounds__(256) void prep2(const float* __restrict__ x,
                                             const float* __restrict__ g,
                                             const float* __restrict__ be,
                                             __hip_bfloat16* __restrict__ y) {
    const int W = DINO, NC = 3;
    int row = blockIdx.x * 4 + (threadIdx.x >> 6);
    int lane = threadIdx.x & 63;
    const float4* xr = (const float4*)(x + (size_t)row * W);
    const float4* g4 = (const float4*)g;
    const float4* b4 = (const float4*)be;
    float4 v[NC];
    float s = 0.f, ss = 0.f;
    #pragma unroll
    for (int i = 0; i < NC; ++i) {
        int c = lane + i * 64;
        float4 t = xr[c];
        v[i] = t;
        s  += t.x + t.y + t.z + t.w;
        ss += t.x * t.x + t.y * t.y + t.z * t.z + t.w * t.w;
    }
    #pragma unroll
    for (int off = 1; off < 64; off <<= 1) {
        s  += __shfl_xor(s, off);
        ss += __shfl_xor(ss, off);
    }
    float mu = s / W;
    float rstd = rsqrtf(ss / W - mu * mu + 1e-5f);
    ushort4* yr = (ushort4*)(y + (size_t)row * W);
    #pragma unroll
    for (int i = 0; i < NC; ++i) {
        int c = lane + i * 64;
        float4 t = v[i];
        float4 gg = g4[c], bb = b4[c];
        ushort4 o;
        o.x = f2bf_bits((t.x - mu) * rstd * gg.x + bb.x);
        o.y = f2bf_bits((t.y - mu) * rstd * gg.y + bb.y);
        o.z = f2bf_bits((t.z - mu) * rstd * gg.z + bb.z);
        o.w = f2bf_bits((t.w - mu) * rstd * gg.w + bb.w);
        yr[c] = o;
    }
}

// =================== stage1: 256x256-tile 8-phase pipelined GEMM ===================
// blocks [0,192)   : KV: xkv[8192,1920] @ WkvT[1536,1920]^T; n<768->kb, n>=768->VT
// blocks [192,216) : Q:  xq[2048,768]  @ WqT[768,768]^T    -> qb
//
// Schedule per K-tile g (4 phases, quadrant = M-half x N-half):
//   P1(A0,B0) stages A1(g+1); P2(A1,B0) stages B1(g+1);
//   P3(A0,B1) stages B0(g+2); P4(A1,B1) stages A0(g+2), vmcnt(4).
// LDS rows are permuted at stage time so each quadrant's rows are a contiguous
// LDS half (A half h = global rows {h*64..h*64+63, 128+h*64..}, B half h =
// {w*64+h*32..+31, w=0..3}); col-groups XOR-swizzled by row&7 on both sides.
#define VM4 asm volatile("s_waitcnt vmcnt(4)" ::: "memory")
#define VM0 asm volatile("s_waitcnt vmcnt(0)" ::: "memory")

#define STAGE_A(d, h, tau) do { \
    int _o = (aRow + (h) * 64) * Kd + (tau) * 64 + cgo; \
    __hip_bfloat16* _dp = SM + (d) * 32768 + (h) * 8192 + wido; \
    glds16(Ag + _o, _dp); \
    glds16(Ag + _o + 128 * Kd, _dp + 4096); \
} while (0)

#define STAGE_B(d, h, tau) do { \
    int _o = (bRow + (h) * 32) * Kd + (tau) * 64 + cgo; \
    __hip_bfloat16* _dp = SM + (d) * 32768 + 16384 + (h) * 8192 + wido; \
    glds16(Bg + _o, _dp); \
    glds16(Bg + _o + 128 * Kd, _dp + 4096); \
} while (0)

#define PHASE(MH, NH, STAGE_STMT, WAIT_STMT) do { \
    const __hip_bfloat16* _Ab = SM + cur * 32768 + (MH) * 8192 + aoff; \
    const __hip_bfloat16* _Bb = SM + cur * 32768 + 16384 + (NH) * 8192 + boff; \
    bf16x8 _a[4][2], _b[2][2]; \
    _Pragma("unroll") \
    for (int i = 0; i < 4; ++i) { \
        _a[i][0] = *(const bf16x8*)(_Ab + i * 1024 + c0); \
        _a[i][1] = *(const bf16x8*)(_Ab + i * 1024 + c1); \
    } \
    _Pragma("unroll") \
    for (int j = 0; j < 2; ++j) { \
        _b[j][0] = *(const bf16x8*)(_Bb + j * 1024 + c0); \
        _b[j][1] = *(const bf16x8*)(_Bb + j * 1024 + c1); \
    } \
    STAGE_STMT; \
    WAIT_STMT; \
    __builtin_amdgcn_sched_barrier(0); \
    __builtin_amdgcn_s_barrier(); \
    __builtin_amdgcn_sched_barrier(0); \
    __builtin_amdgcn_s_setprio(1); \
    _Pragma("unroll") \
    for (int i = 0; i < 4; ++i) \
        _Pragma("unroll") \
        for (int j = 0; j < 2; ++j) { \
            f32x4 _t = acc[(MH) * 4 + i][(NH) * 2 + j]; \
            _t = __builtin_amdgcn_mfma_f32_16x16x32_bf16(_a[i][0], _b[j][0], _t, 0, 0, 0); \
            _t = __builtin_amdgcn_mfma_f32_16x16x32_bf16(_a[i][1], _b[j][1], _t, 0, 0, 0); \
            acc[(MH) * 4 + i][(NH) * 2 + j] = _t; \
        } \
    __builtin_amdgcn_s_setprio(0); \
    __builtin_amdgcn_sched_barrier(0); \
    __builtin_amdgcn_s_barrier(); \
} while (0)

__global__ __launch_bounds__(512, 2) void stage1(const __hip_bfloat16* __restrict__ xq,
                                                 const __hip_bfloat16* __restrict__ WqT,
                                                 const float* __restrict__ bq,
                                                 __hip_bfloat16* __restrict__ qb,
                                                 const __hip_bfloat16* __restrict__ xkv,
                                                 const __hip_bfloat16* __restrict__ WkvT,
                                                 const float* __restrict__ bk,
                                                 const float* __restrict__ bv,
                                                 __hip_bfloat16* __restrict__ kb,
                                                 __hip_bfloat16* __restrict__ VT) {
    __shared__ __hip_bfloat16 SM[65536];   // 128 KiB: [buf2][ A 256x64 | B 256x64 ]
    int bid = blockIdx.x;
    int tid = threadIdx.x;
    int wid = tid >> 6, lane = tid & 63;
    int l4 = lane & 15, lq = lane >> 4;
    int wr = wid >> 2, wc = wid & 3;
    int tr = tid >> 3;                       // 0..63
    int cgo = ((tid & 7) ^ (tr & 7)) * 8;    // swizzled col offset (elems) for staging
    int wido = wid * 512;                    // wave-uniform LDS dest (elems)

    const __hip_bfloat16 *Ag, *Bg;
    int m0, n0, Kd, NT, isQ;
    if (bid < 192) {
        m0 = (bid & 31) * 256; n0 = (bid >> 5) * 256;
        Ag = xkv; Bg = WkvT; Kd = COG; NT = COG / 64; isQ = 0;
    } else {
        int t = bid - 192;
        m0 = (t & 7) * 256; n0 = (t >> 3) * 256;
        Ag = xq; Bg = WqT; Kd = DINO; NT = DINO / 64; isQ = 1;
    }

    const int aRow = m0 + tr;                                  // + h*64 (+rho*128)
    const int bRow = n0 + ((tid >> 8) << 6) + (tr & 31);       // + h*32 (+rho*128)
    const int aoff = (wr * 64 + l4) * 64;
    const int boff = (wc * 32 + l4) * 64;
    const int c0 = ((lq) ^ (l4 & 7)) * 8;
    const int c1 = ((4 + lq) ^ (l4 & 7)) * 8;

    f32x4 acc[8][4];
    #pragma unroll
    for (int i = 0; i < 8; ++i)
        #pragma unroll
        for (int j = 0; j < 4; ++j) acc[i][j] = (f32x4){0.f, 0.f, 0.f, 0.f};

    // prologue: tile 0 complete + A0/B0 of tile 1
    STAGE_A(0, 0, 0); STAGE_B(0, 0, 0); STAGE_A(0, 1, 0); STAGE_B(0, 1, 0);
    STAGE_A(1, 0, 1); STAGE_B(1, 0, 1);
    VM4;
    __builtin_amdgcn_s_barrier();

    for (int g = 0; g < NT; ++g) {
        int cur = g & 1, nxt = cur ^ 1;
        bool s1 = (g + 1 < NT), s2 = (g + 2 < NT);
        PHASE(0, 0, if (s1) STAGE_A(nxt, 1, g + 1), (void)0);
        PHASE(1, 0, if (s1) STAGE_B(nxt, 1, g + 1), (void)0);
        PHASE(0, 1, if (s2) STAGE_B(cur, 0, g + 2), (void)0);
        PHASE(1, 1, if (s2) STAGE_A(cur, 0, g + 2),
              if (s2) { VM4; } else { VM0; });
    }

    // epilogue: C/D layout col=l4, row=lq*4+r (same convention as verified 128-tile kernel)
    if (isQ) {
        #pragma unroll
        for (int ii = 0; ii < 8; ++ii)
            #pragma unroll
            for (int jj = 0; jj < 4; ++jj) {
                int m = m0 + wr * 128 + (ii >> 2) * 64 + (ii & 3) * 16 + lq * 4;
                int n = n0 + wc * 64 + (jj >> 1) * 32 + (jj & 1) * 16 + l4;
                float bb = bq[n];
                #pragma unroll
                for (int r = 0; r < 4; ++r)
                    qb[(size_t)(m + r) * DINO + n] = __float2bfloat16(acc[ii][jj][r] + bb);
            }
    } else if (n0 < 768) {
        #pragma unroll
        for (int ii = 0; ii < 8; ++ii)
            #pragma unroll
            for (int jj = 0; jj < 4; ++jj) {
                int m = m0 + wr * 128 + (ii >> 2) * 64 + (ii & 3) * 16 + lq * 4;
                int n = n0 + wc * 64 + (jj >> 1) * 32 + (jj & 1) * 16 + l4;
                float bb = bk[n];
                #pragma unroll
                for (int r = 0; r < 4; ++r)
                    kb[(size_t)(m + r) * DINO + n] = __float2bfloat16(acc[ii][jj][r] + bb);
            }
    } else {
        #pragma unroll
        for (int ii = 0; ii < 8; ++ii)
            #pragma unroll
            for (int jj = 0; jj < 4; ++jj) {
                int m = m0 + wr * 128 + (ii >> 2) * 64 + (ii & 3) * 16 + lq * 4;
                int nv = n0 - 768 + wc * 64 + (jj >> 1) * 32 + (jj & 1) * 16 + l4;
                float bb = bv[nv];
                #pragma unroll
                for (int r = 0; r < 4; ++r) {
                    int mm = m + r;
                    VT[((size_t)((mm >> 12) * 768 + nv)) * TKV + (mm & 4095)] =
                        __float2bfloat16(acc[ii][jj][r] + bb);
                }
            }
    }
}

// =================== O projection: 64x64 tiles (C^T epilogue -> NCHW fp32) ===================
__global__ __launch_bounds__(256) void gemm_o(const __hip_bfloat16* __restrict__ A,
                                              const __hip_bfloat16* __restrict__ Bt,
                                              const float* __restrict__ bias,
                                              float* __restrict__ out) {
    const int K = DINO;
    __shared__ __hip_bfloat16 As[64 * 64];
    __shared__ __hip_bfloat16 Bs[64 * 64];
    int m0 = blockIdx.x * 64, n0 = blockIdx.y * 64;
    int tid = threadIdx.x, w = tid >> 6, lane = tid & 63;
    int l4 = lane & 15, lq = lane >> 4;
    int mq = (w & 1) * 32, nq = (w >> 1) * 32;
    f32x4 acc[2][2];
    #pragma unroll
    for (int i = 0; i < 2; ++i)
        #pragma unroll
        for (int j = 0; j < 2; ++j) acc[i][j] = (f32x4){0.f, 0.f, 0.f, 0.f};

    int rr = tid >> 3;
    int gc = (tid & 7) ^ (rr & 7);
    const __hip_bfloat16* ag = A  + (size_t)(m0 + rr) * K + gc * 8;
    const __hip_bfloat16* bg = Bt + (size_t)(n0 + rr) * K + gc * 8;
    __hip_bfloat16* asl = As + (w * 8) * 64;
    __hip_bfloat16* bsl = Bs + (w * 8) * 64;
    int sws = l4 & 7;

    for (int k0 = 0; k0 < K; k0 += 64) {
        __syncthreads();
        #pragma unroll
        for (int g = 0; g < 2; ++g) {
            glds16(ag + (size_t)(g * 32) * K + k0, asl + g * 32 * 64);
            glds16(bg + (size_t)(g * 32) * K + k0, bsl + g * 32 * 64);
        }
        __syncthreads();
        #pragma unroll
        for (int h = 0; h < 2; ++h) {
            bf16x8 a[2], b[2];
            #pragma unroll
            for (int i = 0; i < 2; ++i)
                a[i] = *(const bf16x8*)(As + (mq + 16 * i + l4) * 64 + (((h * 4 + lq) ^ sws) * 8));
            #pragma unroll
            for (int j = 0; j < 2; ++j)
                b[j] = *(const bf16x8*)(Bs + (nq + 16 * j + l4) * 64 + (((h * 4 + lq) ^ sws) * 8));
            #pragma unroll
            for (int i = 0; i < 2; ++i)
                #pragma unroll
                for (int j = 0; j < 2; ++j)
                    acc[i][j] = __builtin_amdgcn_mfma_f32_16x16x32_bf16(b[j], a[i], acc[i][j], 0, 0, 0);
        }
    }
    #pragma unroll
    for (int i = 0; i < 2; ++i)
        #pragma unroll
        for (int j = 0; j < 2; ++j)
            #pragma unroll
            for (int r = 0; r < 4; ++r) {
                int n = n0 + nq + 16 * j + lq * 4 + r;
                int m = m0 + mq + 16 * i + l4;
                int b = m >> 10, hw = m & 1023;
                out[((size_t)b * DINO + n) * HWl + hw] = acc[i][j][r] + bias[n];
            }
}

// =================== flash attention: 128-q tile, K/V double-buffered glds ===================
__global__ __launch_bounds__(256) void attn4(const __hip_bfloat16* __restrict__ qb,
                                             const __hip_bfloat16* __restrict__ kb,
                                             const __hip_bfloat16* __restrict__ VT,
                                             const float* __restrict__ tw,
                                             __hip_bfloat16* __restrict__ Opart,
                                             float* __restrict__ lpart) {
    int bid = blockIdx.x;
    int g = bid % 96, qc = bid / 96;
    int s = g & 3, bh = g >> 2;
    int head = bh % NHh, b = bh / NHh;
    int tid = threadIdx.x, w = tid >> 6, lane = tid & 63;
    int l4 = lane & 15, lq = lane >> 4;

    __shared__ __hip_bfloat16 Ks[2 * 64 * 64];
    __shared__ __hip_bfloat16 Vs[2 * 64 * 64];
    __shared__ __hip_bfloat16 Ps[4 * 32 * 64];

    const __hip_bfloat16* qbase = qb + (size_t)(b * HWl + qc * 128 + w * 32 + l4) * DINO + head * 64;
    bf16x8 qA0 = *(const bf16x8*)(qbase + lq * 8);
    bf16x8 qA1 = *(const bf16x8*)(qbase + 32 + lq * 8);
    const __hip_bfloat16* qbase2 = qbase + (size_t)16 * DINO;
    bf16x8 qB0 = *(const bf16x8*)(qbase2 + lq * 8);
    bf16x8 qB1 = *(const bf16x8*)(qbase2 + 32 + lq * 8);

    float c = tw[s] * 0.125f * 1.44269504f;
    float l_iA = 0.f, l_iB = 0.f;
    f32x4 oA[4], oB[4];
    #pragma unroll
    for (int j = 0; j < 4; ++j) { oA[j] = (f32x4){0.f,0.f,0.f,0.f}; oB[j] = (f32x4){0.f,0.f,0.f,0.f}; }

    int rowA = w * 16 + (lane >> 3);
    int cg = (lane & 7) ^ ((lane >> 3) & 7);
    const __hip_bfloat16* kg0 = kb + (size_t)(b * TKV + s * 1024 + rowA) * DINO + head * 64 + cg * 8;
    const __hip_bfloat16* kg1 = kg0 + (size_t)8 * DINO;
    const __hip_bfloat16* vg0 = VT + (size_t)(b * 768 + head * 64 + rowA) * TKV + s * 1024 + cg * 8;
    const __hip_bfloat16* vg1 = vg0 + (size_t)8 * TKV;
    int klo0 = (w * 2 + 0) * 512, klo1 = (w * 2 + 1) * 512;

    int sw0 = (lq ^ (l4 & 7)) * 8;
    int sw1 = ((4 + lq) ^ (l4 & 7)) * 8;
    __hip_bfloat16* PsA = Ps + w * 2048 + l4 * 64;
    __hip_bfloat16* PsB = Ps + w * 2048 + (16 + l4) * 64;

    // prologue: stage tile 0 into buffer 0
    glds16(kg0, Ks + klo0);
    glds16(kg1, Ks + klo1);
    glds16(vg0, Vs + klo0);
    glds16(vg1, Vs + klo1);

    for (int kt = 0; kt < 16; ++kt) {
        int cur = (kt & 1) * 4096;
        __syncthreads();   // drains pending glds (incl. prefetch of this tile)
        if (kt < 15) {
            int nxt = cur ^ 4096;
            glds16(kg0 + (size_t)(kt + 1) * 64 * DINO, Ks + nxt + klo0);
            glds16(kg1 + (size_t)(kt + 1) * 64 * DINO, Ks + nxt + klo1);
            glds16(vg0 + (kt + 1) * 64, Vs + nxt + klo0);
            glds16(vg1 + (kt + 1) * 64, Vs + nxt + klo1);
        }
        const __hip_bfloat16* Kc = Ks + cur;
        const __hip_bfloat16* Vc = Vs + cur;

        f32x4 stA[4], stB[4];
        #pragma unroll
        for (int j = 0; j < 4; ++j) {
            const __hip_bfloat16* kr = Kc + (16 * j + l4) * 64;
            bf16x8 kf0 = *(const bf16x8*)(kr + sw0);
            bf16x8 kf1 = *(const bf16x8*)(kr + sw1);
            f32x4 a = (f32x4){0.f,0.f,0.f,0.f};
            a = __builtin_amdgcn_mfma_f32_16x16x32_bf16(kf0, qA0, a, 0, 0, 0);
            a = __builtin_amdgcn_mfma_f32_16x16x32_bf16(kf1, qA1, a, 0, 0, 0);
            stA[j] = a;
            f32x4 bb = (f32x4){0.f,0.f,0.f,0.f};
            bb = __builtin_amdgcn_mfma_f32_16x16x32_bf16(kf0, qB0, bb, 0, 0, 0);
            bb = __builtin_amdgcn_mfma_f32_16x16x32_bf16(kf1, qB1, bb, 0, 0, 0);
            stB[j] = bb;
        }

        float lsA = 0.f, lsB = 0.f;
        #pragma unroll
        for (int j = 0; j < 4; ++j)
            #pragma unroll
            for (int r = 0; r < 4; ++r) {
                float eA = exp2f(stA[j][r] * c);
                float eB = exp2f(stB[j][r] * c);
                stA[j][r] = eA; lsA += eA;
                stB[j][r] = eB; lsB += eB;
            }
        lsA += __shfl_xor(lsA, 16); lsA += __shfl_xor(lsA, 32);
        lsB += __shfl_xor(lsB, 16); lsB += __shfl_xor(lsB, 32);
        l_iA += lsA; l_iB += lsB;

        #pragma unroll
        for (int j = 0; j < 4; ++j) {
            int off = (((2 * j + (lq >> 1)) ^ (l4 & 7)) << 3) + (lq & 1) * 4;
            ushort4 pA, pB;
            pA.x = f2bf_bits(stA[j][0]); pA.y = f2bf_bits(stA[j][1]);
            pA.z = f2bf_bits(stA[j][2]); pA.w = f2bf_bits(stA[j][3]);
            pB.x = f2bf_bits(stB[j][0]); pB.y = f2bf_bits(stB[j][1]);
            pB.z = f2bf_bits(stB[j][2]); pB.w = f2bf_bits(stB[j][3]);
            *(ushort4*)&PsA[off] = pA;
            *(ushort4*)&PsB[off] = pB;
        }
        bf16x8 paA0 = *(const bf16x8*)(PsA + sw0);
        bf16x8 paA1 = *(const bf16x8*)(PsA + sw1);
        bf16x8 paB0 = *(const bf16x8*)(PsB + sw0);
        bf16x8 paB1 = *(const bf16x8*)(PsB + sw1);

        #pragma unroll
        for (int j = 0; j < 4; ++j) {
            const __hip_bfloat16* vr = Vc + (16 * j + l4) * 64;
            bf16x8 vf0 = *(const bf16x8*)(vr + sw0);
            bf16x8 vf1 = *(const bf16x8*)(vr + sw1);
            oA[j] = __builtin_amdgcn_mfma_f32_16x16x32_bf16(paA0, vf0, oA[j], 0, 0, 0);
            oA[j] = __builtin_amdgcn_mfma_f32_16x16x32_bf16(paA1, vf1, oA[j], 0, 0, 0);
            oB[j] = __builtin_amdgcn_mfma_f32_16x16x32_bf16(paB0, vf0, oB[j], 0, 0, 0);
            oB[j] = __builtin_amdgcn_mfma_f32_16x16x32_bf16(paB1, vf1, oB[j], 0, 0, 0);
        }
    }

    size_t rb = (size_t)s * ROWS_PER_SPLIT + (size_t)(b * NHh + head) * HWl + qc * 128 + w * 32;
    #pragma unroll
    for (int j = 0; j < 4; ++j)
        #pragma unroll
        for (int r = 0; r < 4; ++r) {
            Opart[(rb + lq * 4 + r) * 64 + j * 16 + l4]      = __float2bfloat16(oA[j][r]);
            Opart[(rb + 16 + lq * 4 + r) * 64 + j * 16 + l4] = __float2bfloat16(oB[j][r]);
        }
    if (lq == 0) {
        lpart[rb + l4]      = l_iA;
        lpart[rb + 16 + l4] = l_iB;
    }
}

// =================== combine split partials ===================
__global__ void combine(const __hip_bfloat16* __restrict__ Opart, const float* __restrict__ lpart,
                        __hip_bfloat16* __restrict__ attn) {
    int p = blockIdx.x * 4 + (threadIdx.x >> 6);
    int d = threadIdx.x & 63;
    float L = 0.f, O = 0.f;
    #pragma unroll
    for (int s = 0; s < NSPL; ++s) {
        L += lpart[(size_t)s * ROWS_PER_SPLIT + p];
        O += __bfloat162float(Opart[((size_t)s * ROWS_PER_SPLIT + p) * 64 + d]);
    }
    float res = O / L;
    int q = p & 1023;
    int bh = p >> 10;
    int head = bh % NHh, b = bh / NHh;
    attn[((size_t)(b * HWl + q)) * DINO + head * 64 + d] = __float2bfloat16(res);
}

// =================== launch ===================
extern "C" void kernel_launch(void* const* d_in, const int* in_sizes, int n_in,
                              void* d_out, int out_size, void* d_ws, size_t ws_size,
                              hipStream_t stream) {
    (void)in_sizes; (void)n_in; (void)out_size; (void)ws_size;
    const float* dino = (const float*)d_in[0];
    const float* cog  = (const float*)d_in[1];
    const float* tw   = (const float*)d_in[2];
    const float* Wq   = (const float*)d_in[3];
    const float* bq   = (const float*)d_in[4];
    const float* Wk   = (const float*)d_in[5];
    const float* bk   = (const float*)d_in[6];
    const float* Wv   = (const float*)d_in[7];
    const float* bv   = (const float*)d_in[8];
    const float* Wo   = (const float*)d_in[9];
    const float* bo   = (const float*)d_in[10];
    const float* gq   = (const float*)d_in[11];
    const float* Bq   = (const float*)d_in[12];
    const float* gkv  = (const float*)d_in[13];
    const float* Bkv  = (const float*)d_in[14];

    char* p = (char*)d_ws;
    float* xqT = (float*)p;                    p += (size_t)MQ * DINO * 4;
    __hip_bfloat16* xq = (__hip_bfloat16*)p;   p += (size_t)MQ * DINO * 2;
    char* alias = p;                           p += (size_t)MKV * COG * 2;   // xkv | Opart+lpart
    __hip_bfloat16* xkv = (__hip_bfloat16*)alias;
    __hip_bfloat16* WqT  = (__hip_bfloat16*)p; p += (size_t)DINO * DINO * 2;
    __hip_bfloat16* WkvT = (__hip_bfloat16*)p; p += (size_t)1536 * COG * 2;
    __hip_bfloat16* WoT  = (__hip_bfloat16*)p; p += (size_t)DINO * DINO * 2;
    __hip_bfloat16* qb   = (__hip_bfloat16*)p; p += (size_t)MQ  * DINO * 2;
    __hip_bfloat16* kb   = (__hip_bfloat16*)p; p += (size_t)MKV * DINO * 2;
    __hip_bfloat16* VT   = (__hip_bfloat16*)p; p += (size_t)MKV * DINO * 2;
    __hip_bfloat16* attnb = (__hip_bfloat16*)p; p += (size_t)MQ * DINO * 2;
    __hip_bfloat16* Opart = (__hip_bfloat16*)alias;
    float* lpart = (float*)(alias + (size_t)NSPL * ROWS_PER_SPLIT * 64 * 2);

    prep1<<<8192, 256, 0, stream>>>(dino, cog, gkv, Bkv,
                                    Wq, Wk, Wv, Wo, xqT, xkv, WqT, WkvT, WoT);
    prep2<<<MQ / 4, 256, 0, stream>>>(xqT, gq, Bq, xq);
    stage1<<<216, 512, 0, stream>>>(xq, WqT, bq, qb, xkv, WkvT, bk, bv, kb, VT);
    attn4<<<BB * NHh * 8 * NSPL, 256, 0, stream>>>(qb, kb, VT, tw, Opart, lpart);
    combine<<<ROWS_PER_SPLIT / 4, 256, 0, stream>>>(Opart, lpart, attnb);
    gemm_o<<<dim3(32, 12), 256, 0, stream>>>(attnb, WoT, bo, (float*)d_out);
}

// Round 2
// 255.546 us; speedup vs baseline: 1.0617x; 1.0472x over previous
//
#include <hip/hip_runtime.h>
#include <hip/hip_bf16.h>
#include <math.h>

#define BB   2
#define HWl  1024
#define DINO 768
#define COG  1920
#define NHh  12
#define TKV  4096
#define MQ   (BB*HWl)      // 2048
#define MKV  (BB*TKV)      // 8192
#define NSPL 4
#define ROWS_PER_SPLIT (BB*NHh*HWl)   // 24576

typedef __attribute__((ext_vector_type(8))) short bf16x8;
typedef __attribute__((ext_vector_type(4))) float f32x4;

__device__ __forceinline__ unsigned short f2bf_bits(float f) {
    __hip_bfloat16 h = __float2bfloat16(f);
    return *reinterpret_cast<unsigned short*>(&h);
}

__device__ __forceinline__ void glds16(const __hip_bfloat16* g, __hip_bfloat16* l) {
    __builtin_amdgcn_global_load_lds((const __attribute__((address_space(1))) void*)g,
                                     (__attribute__((address_space(3))) void*)l, 16, 0, 0);
}

// =================== prep1 mega-kernel ===================
// blocks [0,2048)     : LN of cog -> xkv bf16 (wave per row, 4 rows/block)
// blocks [2048,2432)  : dino NCHW -> xqT fp32 transpose (64x64 LDS tiles, coalesced)
// blocks [2432,8192)  : weight transposes -> WqT, WkvT(concat), WoT
__global__ __launch_bounds__(256) void prep1(const float* __restrict__ dino,
                                             const float* __restrict__ cog,
                                             const float* __restrict__ gkv, const float* __restrict__ Bkv,
                                             const float* __restrict__ Wq, const float* __restrict__ Wk,
                                             const float* __restrict__ Wv, const float* __restrict__ Wo,
                                             float* __restrict__ xqT,
                                             __hip_bfloat16* __restrict__ xkv,
                                             __hip_bfloat16* WqT, __hip_bfloat16* WkvT, __hip_bfloat16* WoT) {
    int bid = blockIdx.x, tid = threadIdx.x;
    if (bid < 2048) {
        const int W = COG, W4 = W >> 2, NC = 8;
        int row = bid * 4 + (tid >> 6), lane = tid & 63;
        const float4* xr = (const float4*)(cog + (size_t)row * W);
        const float4* g4 = (const float4*)gkv;
        const float4* b4 = (const float4*)Bkv;
        float4 v[NC];
        float s = 0.f, ss = 0.f;
        #pragma unroll
        for (int i = 0; i < NC; ++i) {
            int c = lane + i * 64;
            float4 t = (c < W4) ? xr[c] : (float4){0.f, 0.f, 0.f, 0.f};
            v[i] = t;
            s  += t.x + t.y + t.z + t.w;
            ss += t.x * t.x + t.y * t.y + t.z * t.z + t.w * t.w;
        }
        #pragma unroll
        for (int off = 1; off < 64; off <<= 1) {
            s  += __shfl_xor(s, off);
            ss += __shfl_xor(ss, off);
        }
        float mu = s / W;
        float rstd = rsqrtf(ss / W - mu * mu + 1e-5f);
        ushort4* yr = (ushort4*)(xkv + (size_t)row * W);
        #pragma unroll
        for (int i = 0; i < NC; ++i) {
            int c = lane + i * 64;
            if (c < W4) {
                float4 t = v[i];
                float4 gg = g4[c], bb = b4[c];
                ushort4 o;
                o.x = f2bf_bits((t.x - mu) * rstd * gg.x + bb.x);
                o.y = f2bf_bits((t.y - mu) * rstd * gg.y + bb.y);
                o.z = f2bf_bits((t.z - mu) * rstd * gg.z + bb.z);
                o.w = f2bf_bits((t.w - mu) * rstd * gg.w + bb.w);
                yr[c] = o;
            }
        }
    } else if (bid < 2432) {
        int t = bid - 2048;                 // 384 = 16 x 12 x 2
        int h0 = (t & 15) * 64;
        int c0 = ((t >> 4) % 12) * 64;
        int b = t / 192;
        __shared__ float T[64][65];
        #pragma unroll
        for (int i = 0; i < 16; ++i) {
            int idx = tid + i * 256;
            int c = idx >> 6, h = idx & 63;
            T[c][h] = dino[((size_t)b * DINO + c0 + c) * HWl + h0 + h];
        }
        __syncthreads();
        #pragma unroll
        for (int i = 0; i < 16; ++i) {
            int idx = tid + i * 256;
            int r = idx >> 6, c = idx & 63;
            xqT[((size_t)b * HWl + h0 + r) * DINO + c0 + c] = T[c][r];
        }
    } else {
        int bid2 = bid - 2432;
        int mid = bid2 / 1440, r = bid2 % 1440;
        int k0 = (r % 60) * 32, n0 = (r / 60) * 32;
        const float* src = (mid == 0) ? Wq : (mid == 1) ? Wk : (mid == 2) ? Wv : Wo;
        __hip_bfloat16* dst;
        int rowoff = 0;
        if (mid == 0) dst = WqT;
        else if (mid == 1) dst = WkvT;
        else if (mid == 2) { dst = WkvT; rowoff = 768; }
        else dst = WoT;
        int K = (mid == 1 || mid == 2) ? COG : DINO;
        if (k0 >= K) return;
        __shared__ float T[32][33];
        #pragma unroll
        for (int i = 0; i < 4; ++i) {
            int idx = tid + i * 256;
            int rr = idx >> 5, c = idx & 31;
            T[rr][c] = src[(size_t)(k0 + rr) * DINO + n0 + c];
        }
        __syncthreads();
        #pragma unroll
        for (int i = 0; i < 4; ++i) {
            int idx = tid + i * 256;
            int rr = idx >> 5, c = idx & 31;
            dst[(size_t)(rowoff + n0 + rr) * K + k0 + c] = __float2bfloat16(T[c][rr]);
        }
    }
}

// =================== prep2: LN of xqT rows -> xq bf16 ===================
__global__ __launch_bounds__(256) void prep2(const float* __restrict__ x,
                                             const float* __restrict__ g,
                                             const float* __restrict__ be,
                                             __hip_bfloat16* __restrict__ y) {
    const int W = DINO, NC = 3;
    int row = blockIdx.x * 4 + (threadIdx.x >> 6);
    int lane = threadIdx.x & 63;
    const float4* xr = (const float4*)(x + (size_t)row * W);
    const float4* g4 = (const float4*)g;
    const float4* b4 = (const float4*)be;
    float4 v[NC];
    float s = 0.f, ss = 0.f;
    #pragma unroll
    for (int i = 0; i < NC; ++i) {
        int c = lane + i * 64;
        float4 t = xr[c];
        v[i] = t;
        s  += t.x + t.y + t.z + t.w;
        ss += t.x * t.x + t.y * t.y + t.z * t.z + t.w * t.w;
    }
    #pragma unroll
    for (int off = 1; off < 64; off <<= 1) {
        s  += __shfl_xor(s, off);
        ss += __shfl_xor(ss, off);
    }
    float mu = s / W;
    float rstd = rsqrtf(ss / W - mu * mu + 1e-5f);
    ushort4* yr = (ushort4*)(y + (size_t)row * W);
    #pragma unroll
    for (int i = 0; i < NC; ++i) {
        int c = lane + i * 64;
        float4 t = v[i];
        float4 gg = g4[c], bb = b4[c];
        ushort4 o;
        o.x = f2bf_bits((t.x - mu) * rstd * gg.x + bb.x);
        o.y = f2bf_bits((t.y - mu) * rstd * gg.y + bb.y);
        o.z = f2bf_bits((t.z - mu) * rstd * gg.z + bb.z);
        o.w = f2bf_bits((t.w - mu) * rstd * gg.w + bb.w);
        yr[c] = o;
    }
}

// =================== stage1: 256x256-tile pipelined GEMM, fragment-reuse phases ===================
// blocks [0,192)   : KV: xkv[8192,1920] @ WkvT[1536,1920]^T; n<768->kb, n>=768->VT
// blocks [192,216) : Q:  xq[2048,768]  @ WqT[768,768]^T    -> qb
//
// Phase order (0,0)->(0,1)->(1,1)->(1,0): consecutive phases share one operand,
// so LDS reads per K-tile = A panel once + B panel once (24 x ds_read_b128/wave
// instead of 48). Stage issue order A0,B0,B1,A1 (one half per phase into nxt)
// matches next tile's read order; uniform vmcnt(4) guarantees the half staged
// 3 phases ago is complete. One barrier per phase (after the vmcnt): stages hit
// only nxt, reads only cur, so the leading barrier covers the only cross-wave
// hazard (all waves' vmcnt passed before dependent reads).
#define VM4 asm volatile("s_waitcnt vmcnt(4)" ::: "memory")
#define VM2 asm volatile("s_waitcnt vmcnt(2)" ::: "memory")
#define VM0 asm volatile("s_waitcnt vmcnt(0)" ::: "memory")

#define STAGE_A(d, h, tau) do { \
    int _o = (aRow + (h) * 64) * Kd + (tau) * 64 + cgo; \
    __hip_bfloat16* _dp = SM + (d) * 32768 + (h) * 8192 + wido; \
    glds16(Ag + _o, _dp); \
    glds16(Ag + _o + 128 * Kd, _dp + 4096); \
} while (0)

#define STAGE_B(d, h, tau) do { \
    int _o = (bRow + (h) * 32) * Kd + (tau) * 64 + cgo; \
    __hip_bfloat16* _dp = SM + (d) * 32768 + 16384 + (h) * 8192 + wido; \
    glds16(Bg + _o, _dp); \
    glds16(Bg + _o + 128 * Kd, _dp + 4096); \
} while (0)

#define LDS_A_FRAG(dst, MH) do { \
    const __hip_bfloat16* _Ab = SM + cur * 32768 + (MH) * 8192 + aoff; \
    _Pragma("unroll") \
    for (int i = 0; i < 4; ++i) { \
        dst[i][0] = *(const bf16x8*)(_Ab + i * 1024 + c0); \
        dst[i][1] = *(const bf16x8*)(_Ab + i * 1024 + c1); \
    } \
} while (0)

#define LDS_B_FRAG(dst, NH) do { \
    const __hip_bfloat16* _Bb = SM + cur * 32768 + 16384 + (NH) * 8192 + boff; \
    _Pragma("unroll") \
    for (int j = 0; j < 2; ++j) { \
        dst[j][0] = *(const bf16x8*)(_Bb + j * 1024 + c0); \
        dst[j][1] = *(const bf16x8*)(_Bb + j * 1024 + c1); \
    } \
} while (0)

#define BARRIER_MFMA(MH, NH, af, bf) do { \
    __builtin_amdgcn_sched_barrier(0); \
    __builtin_amdgcn_s_barrier(); \
    __builtin_amdgcn_sched_barrier(0); \
    __builtin_amdgcn_s_setprio(1); \
    _Pragma("unroll") \
    for (int i = 0; i < 4; ++i) \
        _Pragma("unroll") \
        for (int j = 0; j < 2; ++j) { \
            f32x4 _t = acc[(MH) * 4 + i][(NH) * 2 + j]; \
            _t = __builtin_amdgcn_mfma_f32_16x16x32_bf16(af[i][0], bf[j][0], _t, 0, 0, 0); \
            _t = __builtin_amdgcn_mfma_f32_16x16x32_bf16(af[i][1], bf[j][1], _t, 0, 0, 0); \
            acc[(MH) * 4 + i][(NH) * 2 + j] = _t; \
        } \
    __builtin_amdgcn_s_setprio(0); \
    __builtin_amdgcn_sched_barrier(0); \
} while (0)

__global__ __launch_bounds__(512, 2) void stage1(const __hip_bfloat16* __restrict__ xq,
                                                 const __hip_bfloat16* __restrict__ WqT,
                                                 const float* __restrict__ bq,
                                                 __hip_bfloat16* __restrict__ qb,
                                                 const __hip_bfloat16* __restrict__ xkv,
                                                 const __hip_bfloat16* __restrict__ WkvT,
                                                 const float* __restrict__ bk,
                                                 const float* __restrict__ bv,
                                                 __hip_bfloat16* __restrict__ kb,
                                                 __hip_bfloat16* __restrict__ VT) {
    __shared__ __hip_bfloat16 SM[65536];   // 128 KiB: [buf2][ A 256x64 | B 256x64 ]
    int bid = blockIdx.x;
    int tid = threadIdx.x;
    int wid = tid >> 6, lane = tid & 63;
    int l4 = lane & 15, lq = lane >> 4;
    int wr = wid >> 2, wc = wid & 3;
    int tr = tid >> 3;                       // 0..63
    int cgo = ((tid & 7) ^ (tr & 7)) * 8;    // swizzled col offset (elems) for staging
    int wido = wid * 512;                    // wave-uniform LDS dest (elems)

    const __hip_bfloat16 *Ag, *Bg;
    int m0, n0, Kd, NT, isQ;
    if (bid < 192) {
        m0 = (bid & 31) * 256; n0 = (bid >> 5) * 256;
        Ag = xkv; Bg = WkvT; Kd = COG; NT = COG / 64; isQ = 0;
    } else {
        int t = bid - 192;
        m0 = (t & 7) * 256; n0 = (t >> 3) * 256;
        Ag = xq; Bg = WqT; Kd = DINO; NT = DINO / 64; isQ = 1;
    }

    const int aRow = m0 + tr;                                  // + h*64 (+rho*128)
    const int bRow = n0 + ((tid >> 8) << 6) + (tr & 31);       // + h*32 (+rho*128)
    const int aoff = (wr * 64 + l4) * 64;
    const int boff = (wc * 32 + l4) * 64;
    const int c0 = ((lq) ^ (l4 & 7)) * 8;
    const int c1 = ((4 + lq) ^ (l4 & 7)) * 8;

    f32x4 acc[8][4];
    #pragma unroll
    for (int i = 0; i < 8; ++i)
        #pragma unroll
        for (int j = 0; j < 4; ++j) acc[i][j] = (f32x4){0.f, 0.f, 0.f, 0.f};

    bf16x8 a0[4][2], a1[4][2], b0[2][2], b1[2][2];

    // prologue: stage full tile 0 (issue order = read order), drain
    STAGE_A(0, 0, 0); STAGE_B(0, 0, 0); STAGE_B(0, 1, 0); STAGE_A(0, 1, 0);
    VM0;
    __builtin_amdgcn_s_barrier();

    for (int g = 0; g < NT; ++g) {
        int cur = g & 1, nxt = cur ^ 1;
        bool s1 = (g + 1 < NT);
        // P1: reads A0,B0 ; stage A0(g+1) ; MFMA (0,0)
        LDS_A_FRAG(a0, 0);
        LDS_B_FRAG(b0, 0);
        if (s1) { STAGE_A(nxt, 0, g + 1); VM4; } else { VM2; }
        BARRIER_MFMA(0, 0, a0, b0);
        // P2: reads B1 ; stage B0(g+1) ; MFMA (0,1)  [a0 reused from regs]
        LDS_B_FRAG(b1, 1);
        if (s1) { STAGE_B(nxt, 0, g + 1); VM4; } else { VM0; }
        BARRIER_MFMA(0, 1, a0, b1);
        // P3: reads A1 ; stage B1(g+1) ; MFMA (1,1)  [b1 reused]
        LDS_A_FRAG(a1, 1);
        if (s1) { STAGE_B(nxt, 1, g + 1); }
        BARRIER_MFMA(1, 1, a1, b1);
        // P4: no LDS reads ; stage A1(g+1) ; MFMA (1,0)  [a1, b0 reused]
        if (s1) { STAGE_A(nxt, 1, g + 1); VM4; }
        BARRIER_MFMA(1, 0, a1, b0);
    }

    // epilogue: C/D layout col=l4, row=lq*4+r
    if (isQ) {
        #pragma unroll
        for (int ii = 0; ii < 8; ++ii)
            #pragma unroll
            for (int jj = 0; jj < 4; ++jj) {
                int m = m0 + wr * 128 + (ii >> 2) * 64 + (ii & 3) * 16 + lq * 4;
                int n = n0 + wc * 64 + (jj >> 1) * 32 + (jj & 1) * 16 + l4;
                float bb = bq[n];
                #pragma unroll
                for (int r = 0; r < 4; ++r)
                    qb[(size_t)(m + r) * DINO + n] = __float2bfloat16(acc[ii][jj][r] + bb);
            }
    } else if (n0 < 768) {
        #pragma unroll
        for (int ii = 0; ii < 8; ++ii)
            #pragma unroll
            for (int jj = 0; jj < 4; ++jj) {
                int m = m0 + wr * 128 + (ii >> 2) * 64 + (ii & 3) * 16 + lq * 4;
                int n = n0 + wc * 64 + (jj >> 1) * 32 + (jj & 1) * 16 + l4;
                float bb = bk[n];
                #pragma unroll
                for (int r = 0; r < 4; ++r)
                    kb[(size_t)(m + r) * DINO + n] = __float2bfloat16(acc[ii][jj][r] + bb);
            }
    } else {
        #pragma unroll
        for (int ii = 0; ii < 8; ++ii)
            #pragma unroll
            for (int jj = 0; jj < 4; ++jj) {
                int m = m0 + wr * 128 + (ii >> 2) * 64 + (ii & 3) * 16 + lq * 4;
                int nv = n0 - 768 + wc * 64 + (jj >> 1) * 32 + (jj & 1) * 16 + l4;
                float bb = bv[nv];
                #pragma unroll
                for (int r = 0; r < 4; ++r) {
                    int mm = m + r;
                    VT[((size_t)((mm >> 12) * 768 + nv)) * TKV + (mm & 4095)] =
                        __float2bfloat16(acc[ii][jj][r] + bb);
                }
            }
    }
}

// =================== O projection: 64x64 tiles (C^T epilogue -> NCHW fp32) ===================
__global__ __launch_bounds__(256) void gemm_o(const __hip_bfloat16* __restrict__ A,
                                              const __hip_bfloat16* __restrict__ Bt,
                                              const float* __restrict__ bias,
                                              float* __restrict__ out) {
    const int K = DINO;
    __shared__ __hip_bfloat16 As[64 * 64];
    __shared__ __hip_bfloat16 Bs[64 * 64];
    int m0 = blockIdx.x * 64, n0 = blockIdx.y * 64;
    int tid = threadIdx.x, w = tid >> 6, lane = tid & 63;
    int l4 = lane & 15, lq = lane >> 4;
    int mq = (w & 1) * 32, nq = (w >> 1) * 32;
    f32x4 acc[2][2];
    #pragma unroll
    for (int i = 0; i < 2; ++i)
        #pragma unroll
        for (int j = 0; j < 2; ++j) acc[i][j] = (f32x4){0.f, 0.f, 0.f, 0.f};

    int rr = tid >> 3;
    int gc = (tid & 7) ^ (rr & 7);
    const __hip_bfloat16* ag = A  + (size_t)(m0 + rr) * K + gc * 8;
    const __hip_bfloat16* bg = Bt + (size_t)(n0 + rr) * K + gc * 8;
    __hip_bfloat16* asl = As + (w * 8) * 64;
    __hip_bfloat16* bsl = Bs + (w * 8) * 64;
    int sws = l4 & 7;

    for (int k0 = 0; k0 < K; k0 += 64) {
        __syncthreads();
        #pragma unroll
        for (int g = 0; g < 2; ++g) {
            glds16(ag + (size_t)(g * 32) * K + k0, asl + g * 32 * 64);
            glds16(bg + (size_t)(g * 32) * K + k0, bsl + g * 32 * 64);
        }
        __syncthreads();
        #pragma unroll
        for (int h = 0; h < 2; ++h) {
            bf16x8 a[2], b[2];
            #pragma unroll
            for (int i = 0; i < 2; ++i)
                a[i] = *(const bf16x8*)(As + (mq + 16 * i + l4) * 64 + (((h * 4 + lq) ^ sws) * 8));
            #pragma unroll
            for (int j = 0; j < 2; ++j)
                b[j] = *(const bf16x8*)(Bs + (nq + 16 * j + l4) * 64 + (((h * 4 + lq) ^ sws) * 8));
            #pragma unroll
            for (int i = 0; i < 2; ++i)
                #pragma unroll
                for (int j = 0; j < 2; ++j)
                    acc[i][j] = __builtin_amdgcn_mfma_f32_16x16x32_bf16(b[j], a[i], acc[i][j], 0, 0, 0);
        }
    }
    #pragma unroll
    for (int i = 0; i < 2; ++i)
        #pragma unroll
        for (int j = 0; j < 2; ++j)
            #pragma unroll
            for (int r = 0; r < 4; ++r) {
                int n = n0 + nq + 16 * j + lq * 4 + r;
                int m = m0 + mq + 16 * i + l4;
                int b = m >> 10, hw = m & 1023;
                out[((size_t)b * DINO + n) * HWl + hw] = acc[i][j][r] + bias[n];
            }
}

// =================== flash attention: 128-q tile, K/V double-buffered glds ===================
__global__ __launch_bounds__(256) void attn4(const __hip_bfloat16* __restrict__ qb,
                                             const __hip_bfloat16* __restrict__ kb,
                                             const __hip_bfloat16* __restrict__ VT,
                                             const float* __restrict__ tw,
                                             __hip_bfloat16* __restrict__ Opart,
                                             float* __restrict__ lpart) {
    int bid = blockIdx.x;
    int g = bid % 96, qc = bid / 96;
    int s = g & 3, bh = g >> 2;
    int head = bh % NHh, b = bh / NHh;
    int tid = threadIdx.x, w = tid >> 6, lane = tid & 63;
    int l4 = lane & 15, lq = lane >> 4;

    __shared__ __hip_bfloat16 Ks[2 * 64 * 64];
    __shared__ __hip_bfloat16 Vs[2 * 64 * 64];
    __shared__ __hip_bfloat16 Ps[4 * 32 * 64];

    const __hip_bfloat16* qbase = qb + (size_t)(b * HWl + qc * 128 + w * 32 + l4) * DINO + head * 64;
    bf16x8 qA0 = *(const bf16x8*)(qbase + lq * 8);
    bf16x8 qA1 = *(const bf16x8*)(qbase + 32 + lq * 8);
    const __hip_bfloat16* qbase2 = qbase + (size_t)16 * DINO;
    bf16x8 qB0 = *(const bf16x8*)(qbase2 + lq * 8);
    bf16x8 qB1 = *(const bf16x8*)(qbase2 + 32 + lq * 8);

    float c = tw[s] * 0.125f * 1.44269504f;
    float l_iA = 0.f, l_iB = 0.f;
    f32x4 oA[4], oB[4];
    #pragma unroll
    for (int j = 0; j < 4; ++j) { oA[j] = (f32x4){0.f,0.f,0.f,0.f}; oB[j] = (f32x4){0.f,0.f,0.f,0.f}; }

    int rowA = w * 16 + (lane >> 3);
    int cg = (lane & 7) ^ ((lane >> 3) & 7);
    const __hip_bfloat16* kg0 = kb + (size_t)(b * TKV + s * 1024 + rowA) * DINO + head * 64 + cg * 8;
    const __hip_bfloat16* kg1 = kg0 + (size_t)8 * DINO;
    const __hip_bfloat16* vg0 = VT + (size_t)(b * 768 + head * 64 + rowA) * TKV + s * 1024 + cg * 8;
    const __hip_bfloat16* vg1 = vg0 + (size_t)8 * TKV;
    int klo0 = (w * 2 + 0) * 512, klo1 = (w * 2 + 1) * 512;

    int sw0 = (lq ^ (l4 & 7)) * 8;
    int sw1 = ((4 + lq) ^ (l4 & 7)) * 8;
    __hip_bfloat16* PsA = Ps + w * 2048 + l4 * 64;
    __hip_bfloat16* PsB = Ps + w * 2048 + (16 + l4) * 64;

    // prologue: stage tile 0 into buffer 0
    glds16(kg0, Ks + klo0);
    glds16(kg1, Ks + klo1);
    glds16(vg0, Vs + klo0);
    glds16(vg1, Vs + klo1);

    for (int kt = 0; kt < 16; ++kt) {
        int cur = (kt & 1) * 4096;
        __syncthreads();   // drains pending glds (incl. prefetch of this tile)
        if (kt < 15) {
            int nxt = cur ^ 4096;
            glds16(kg0 + (size_t)(kt + 1) * 64 * DINO, Ks + nxt + klo0);
            glds16(kg1 + (size_t)(kt + 1) * 64 * DINO, Ks + nxt + klo1);
            glds16(vg0 + (kt + 1) * 64, Vs + nxt + klo0);
            glds16(vg1 + (kt + 1) * 64, Vs + nxt + klo1);
        }
        const __hip_bfloat16* Kc = Ks + cur;
        const __hip_bfloat16* Vc = Vs + cur;

        f32x4 stA[4], stB[4];
        #pragma unroll
        for (int j = 0; j < 4; ++j) {
            const __hip_bfloat16* kr = Kc + (16 * j + l4) * 64;
            bf16x8 kf0 = *(const bf16x8*)(kr + sw0);
            bf16x8 kf1 = *(const bf16x8*)(kr + sw1);
            f32x4 a = (f32x4){0.f,0.f,0.f,0.f};
            a = __builtin_amdgcn_mfma_f32_16x16x32_bf16(kf0, qA0, a, 0, 0, 0);
            a = __builtin_amdgcn_mfma_f32_16x16x32_bf16(kf1, qA1, a, 0, 0, 0);
            stA[j] = a;
            f32x4 bb = (f32x4){0.f,0.f,0.f,0.f};
            bb = __builtin_amdgcn_mfma_f32_16x16x32_bf16(kf0, qB0, bb, 0, 0, 0);
            bb = __builtin_amdgcn_mfma_f32_16x16x32_bf16(kf1, qB1, bb, 0, 0, 0);
            stB[j] = bb;
        }

        float lsA = 0.f, lsB = 0.f;
        #pragma unroll
        for (int j = 0; j < 4; ++j)
            #pragma unroll
            for (int r = 0; r < 4; ++r) {
                float eA = exp2f(stA[j][r] * c);
                float eB = exp2f(stB[j][r] * c);
                stA[j][r] = eA; lsA += eA;
                stB[j][r] = eB; lsB += eB;
            }
        lsA += __shfl_xor(lsA, 16); lsA += __shfl_xor(lsA, 32);
        lsB += __shfl_xor(lsB, 16); lsB += __shfl_xor(lsB, 32);
        l_iA += lsA; l_iB += lsB;

        #pragma unroll
        for (int j = 0; j < 4; ++j) {
            int off = (((2 * j + (lq >> 1)) ^ (l4 & 7)) << 3) + (lq & 1) * 4;
            ushort4 pA, pB;
            pA.x = f2bf_bits(stA[j][0]); pA.y = f2bf_bits(stA[j][1]);
            pA.z = f2bf_bits(stA[j][2]); pA.w = f2bf_bits(stA[j][3]);
            pB.x = f2bf_bits(stB[j][0]); pB.y = f2bf_bits(stB[j][1]);
            pB.z = f2bf_bits(stB[j][2]); pB.w = f2bf_bits(stB[j][3]);
            *(ushort4*)&PsA[off] = pA;
            *(ushort4*)&PsB[off] = pB;
        }
        bf16x8 paA0 = *(const bf16x8*)(PsA + sw0);
        bf16x8 paA1 = *(const bf16x8*)(PsA + sw1);
        bf16x8 paB0 = *(const bf16x8*)(PsB + sw0);
        bf16x8 paB1 = *(const bf16x8*)(PsB + sw1);

        #pragma unroll
        for (int j = 0; j < 4; ++j) {
            const __hip_bfloat16* vr = Vc + (16 * j + l4) * 64;
            bf16x8 vf0 = *(const bf16x8*)(vr + sw0);
            bf16x8 vf1 = *(const bf16x8*)(vr + sw1);
            oA[j] = __builtin_amdgcn_mfma_f32_16x16x32_bf16(paA0, vf0, oA[j], 0, 0, 0);
            oA[j] = __builtin_amdgcn_mfma_f32_16x16x32_bf16(paA1, vf1, oA[j], 0, 0, 0);
            oB[j] = __builtin_amdgcn_mfma_f32_16x16x32_bf16(paB0, vf0, oB[j], 0, 0, 0);
            oB[j] = __builtin_amdgcn_mfma_f32_16x16x32_bf16(paB1, vf1, oB[j], 0, 0, 0);
        }
    }

    size_t rb = (size_t)s * ROWS_PER_SPLIT + (size_t)(b * NHh + head) * HWl + qc * 128 + w * 32;
    #pragma unroll
    for (int j = 0; j < 4; ++j)
        #pragma unroll
        for (int r = 0; r < 4; ++r) {
            Opart[(rb + lq * 4 + r) * 64 + j * 16 + l4]      = __float2bfloat16(oA[j][r]);
            Opart[(rb + 16 + lq * 4 + r) * 64 + j * 16 + l4] = __float2bfloat16(oB[j][r]);
        }
    if (lq == 0) {
        lpart[rb + l4]      = l_iA;
        lpart[rb + 16 + l4] = l_iB;
    }
}

// =================== combine split partials ===================
__global__ void combine(const __hip_bfloat16* __restrict__ Opart, const float* __restrict__ lpart,
                        __hip_bfloat16* __restrict__ attn) {
    int p = blockIdx.x * 4 + (threadIdx.x >> 6);
    int d = threadIdx.x & 63;
    float L = 0.f, O = 0.f;
    #pragma unroll
    for (int s = 0; s < NSPL; ++s) {
        L += lpart[(size_t)s * ROWS_PER_SPLIT + p];
        O += __bfloat162float(Opart[((size_t)s * ROWS_PER_SPLIT + p) * 64 + d]);
    }
    float res = O / L;
    int q = p & 1023;
    int bh = p >> 10;
    int head = bh % NHh, b = bh / NHh;
    attn[((size_t)(b * HWl + q)) * DINO + head * 64 + d] = __float2bfloat16(res);
}

// =================== launch ===================
extern "C" void kernel_launch(void* const* d_in, const int* in_sizes, int n_in,
                              void* d_out, int out_size, void* d_ws, size_t ws_size,
                              hipStream_t stream) {
    (void)in_sizes; (void)n_in; (void)out_size; (void)ws_size;
    const float* dino = (const float*)d_in[0];
    const float* cog  = (const float*)d_in[1];
    const float* tw   = (const float*)d_in[2];
    const float* Wq   = (const float*)d_in[3];
    const float* bq   = (const float*)d_in[4];
    const float* Wk   = (const float*)d_in[5];
    const float* bk   = (const float*)d_in[6];
    const float* Wv   = (const float*)d_in[7];
    const float* bv   = (const float*)d_in[8];
    const float* Wo   = (const float*)d_in[9];
    const float* bo   = (const float*)d_in[10];
    const float* gq   = (const float*)d_in[11];
    const float* Bq   = (const float*)d_in[12];
    const float* gkv  = (const float*)d_in[13];
    const float* Bkv  = (const float*)d_in[14];

    char* p = (char*)d_ws;
    float* xqT = (float*)p;                    p += (size_t)MQ * DINO * 4;
    __hip_bfloat16* xq = (__hip_bfloat16*)p;   p += (size_t)MQ * DINO * 2;
    char* alias = p;                           p += (size_t)MKV * COG * 2;   // xkv | Opart+lpart
    __hip_bfloat16* xkv = (__hip_bfloat16*)alias;
    __hip_bfloat16* WqT  = (__hip_bfloat16*)p; p += (size_t)DINO * DINO * 2;
    __hip_bfloat16* WkvT = (__hip_bfloat16*)p; p += (size_t)1536 * COG * 2;
    __hip_bfloat16* WoT  = (__hip_bfloat16*)p; p += (size_t)DINO * DINO * 2;
    __hip_bfloat16* qb   = (__hip_bfloat16*)p; p += (size_t)MQ  * DINO * 2;
    __hip_bfloat16* kb   = (__hip_bfloat16*)p; p += (size_t)MKV * DINO * 2;
    __hip_bfloat16* VT   = (__hip_bfloat16*)p; p += (size_t)MKV * DINO * 2;
    __hip_bfloat16* attnb = (__hip_bfloat16*)p; p += (size_t)MQ * DINO * 2;
    __hip_bfloat16* Opart = (__hip_bfloat16*)alias;
    float* lpart = (float*)(alias + (size_t)NSPL * ROWS_PER_SPLIT * 64 * 2);

    prep1<<<8192, 256, 0, stream>>>(dino, cog, gkv, Bkv,
                                    Wq, Wk, Wv, Wo, xqT, xkv, WqT, WkvT, WoT);
    prep2<<<MQ / 4, 256, 0, stream>>>(xqT, gq, Bq, xq);
    stage1<<<216, 512, 0, stream>>>(xq, WqT, bq, qb, xkv, WkvT, bk, bv, kb, VT);
    attn4<<<BB * NHh * 8 * NSPL, 256, 0, stream>>>(qb, kb, VT, tw, Opart, lpart);
    combine<<<ROWS_PER_SPLIT / 4, 256, 0, stream>>>(Opart, lpart, attnb);
    gemm_o<<<dim3(32, 12), 256, 0, stream>>>(attnb, WoT, bo, (float*)d_out);
}

// Round 3
// 255.512 us; speedup vs baseline: 1.0618x; 1.0001x over previous
//
#include <hip/hip_runtime.h>
#include <hip/hip_bf16.h>
#include <math.h>

#define BB   2
#define HWl  1024
#define DINO 768
#define COG  1920
#define NHh  12
#define TKV  4096
#define MQ   (BB*HWl)      // 2048
#define MKV  (BB*TKV)      // 8192
#define NSPL 4
#define ROWS_PER_SPLIT (BB*NHh*HWl)   // 24576

typedef __attribute__((ext_vector_type(8))) short bf16x8;
typedef __attribute__((ext_vector_type(4))) float f32x4;

__device__ __forceinline__ unsigned short f2bf_bits(float f) {
    __hip_bfloat16 h = __float2bfloat16(f);
    return *reinterpret_cast<unsigned short*>(&h);
}

__device__ __forceinline__ void glds16(const __hip_bfloat16* g, __hip_bfloat16* l) {
    __builtin_amdgcn_global_load_lds((const __attribute__((address_space(1))) void*)g,
                                     (__attribute__((address_space(3))) void*)l, 16, 0, 0);
}

// =================== prep1 mega-kernel ===================
// blocks [0,2048)     : LN of cog -> xkv bf16 (wave per row, 4 rows/block)
// blocks [2048,2432)  : dino NCHW -> xqT fp32 transpose (64x64 LDS tiles, coalesced)
// blocks [2432,8192)  : weight transposes -> WqT, WkvT(concat), WoT
__global__ __launch_bounds__(256) void prep1(const float* __restrict__ dino,
                                             const float* __restrict__ cog,
                                             const float* __restrict__ gkv, const float* __restrict__ Bkv,
                                             const float* __restrict__ Wq, const float* __restrict__ Wk,
                                             const float* __restrict__ Wv, const float* __restrict__ Wo,
                                             float* __restrict__ xqT,
                                             __hip_bfloat16* __restrict__ xkv,
                                             __hip_bfloat16* WqT, __hip_bfloat16* WkvT, __hip_bfloat16* WoT) {
    int bid = blockIdx.x, tid = threadIdx.x;
    if (bid < 2048) {
        const int W = COG, W4 = W >> 2, NC = 8;
        int row = bid * 4 + (tid >> 6), lane = tid & 63;
        const float4* xr = (const float4*)(cog + (size_t)row * W);
        const float4* g4 = (const float4*)gkv;
        const float4* b4 = (const float4*)Bkv;
        float4 v[NC];
        float s = 0.f, ss = 0.f;
        #pragma unroll
        for (int i = 0; i < NC; ++i) {
            int c = lane + i * 64;
            float4 t = (c < W4) ? xr[c] : (float4){0.f, 0.f, 0.f, 0.f};
            v[i] = t;
            s  += t.x + t.y + t.z + t.w;
            ss += t.x * t.x + t.y * t.y + t.z * t.z + t.w * t.w;
        }
        #pragma unroll
        for (int off = 1; off < 64; off <<= 1) {
            s  += __shfl_xor(s, off);
            ss += __shfl_xor(ss, off);
        }
        float mu = s / W;
        float rstd = rsqrtf(ss / W - mu * mu + 1e-5f);
        ushort4* yr = (ushort4*)(xkv + (size_t)row * W);
        #pragma unroll
        for (int i = 0; i < NC; ++i) {
            int c = lane + i * 64;
            if (c < W4) {
                float4 t = v[i];
                float4 gg = g4[c], bb = b4[c];
                ushort4 o;
                o.x = f2bf_bits((t.x - mu) * rstd * gg.x + bb.x);
                o.y = f2bf_bits((t.y - mu) * rstd * gg.y + bb.y);
                o.z = f2bf_bits((t.z - mu) * rstd * gg.z + bb.z);
                o.w = f2bf_bits((t.w - mu) * rstd * gg.w + bb.w);
                yr[c] = o;
            }
        }
    } else if (bid < 2432) {
        int t = bid - 2048;                 // 384 = 16 x 12 x 2
        int h0 = (t & 15) * 64;
        int c0 = ((t >> 4) % 12) * 64;
        int b = t / 192;
        __shared__ float T[64][65];
        #pragma unroll
        for (int i = 0; i < 16; ++i) {
            int idx = tid + i * 256;
            int c = idx >> 6, h = idx & 63;
            T[c][h] = dino[((size_t)b * DINO + c0 + c) * HWl + h0 + h];
        }
        __syncthreads();
        #pragma unroll
        for (int i = 0; i < 16; ++i) {
            int idx = tid + i * 256;
            int r = idx >> 6, c = idx & 63;
            xqT[((size_t)b * HWl + h0 + r) * DINO + c0 + c] = T[c][r];
        }
    } else {
        int bid2 = bid - 2432;
        int mid = bid2 / 1440, r = bid2 % 1440;
        int k0 = (r % 60) * 32, n0 = (r / 60) * 32;
        const float* src = (mid == 0) ? Wq : (mid == 1) ? Wk : (mid == 2) ? Wv : Wo;
        __hip_bfloat16* dst;
        int rowoff = 0;
        if (mid == 0) dst = WqT;
        else if (mid == 1) dst = WkvT;
        else if (mid == 2) { dst = WkvT; rowoff = 768; }
        else dst = WoT;
        int K = (mid == 1 || mid == 2) ? COG : DINO;
        if (k0 >= K) return;
        __shared__ float T[32][33];
        #pragma unroll
        for (int i = 0; i < 4; ++i) {
            int idx = tid + i * 256;
            int rr = idx >> 5, c = idx & 31;
            T[rr][c] = src[(size_t)(k0 + rr) * DINO + n0 + c];
        }
        __syncthreads();
        #pragma unroll
        for (int i = 0; i < 4; ++i) {
            int idx = tid + i * 256;
            int rr = idx >> 5, c = idx & 31;
            dst[(size_t)(rowoff + n0 + rr) * K + k0 + c] = __float2bfloat16(T[c][rr]);
        }
    }
}

// =================== prep2: LN of xqT rows -> xq bf16 ===================
__global__ __launch_bounds__(256) void prep2(const float* __restrict__ x,
                                             const float* __restrict__ g,
                                             const float* __restrict__ be,
                                             __hip_bfloat16* __restrict__ y) {
    const int W = DINO, NC = 3;
    int row = blockIdx.x * 4 + (threadIdx.x >> 6);
    int lane = threadIdx.x & 63;
    const float4* xr = (const float4*)(x + (size_t)row * W);
    const float4* g4 = (const float4*)g;
    const float4* b4 = (const float4*)be;
    float4 v[NC];
    float s = 0.f, ss = 0.f;
    #pragma unroll
    for (int i = 0; i < NC; ++i) {
        int c = lane + i * 64;
        float4 t = xr[c];
        v[i] = t;
        s  += t.x + t.y + t.z + t.w;
        ss += t.x * t.x + t.y * t.y + t.z * t.z + t.w * t.w;
    }
    #pragma unroll
    for (int off = 1; off < 64; off <<= 1) {
        s  += __shfl_xor(s, off);
        ss += __shfl_xor(ss, off);
    }
    float mu = s / W;
    float rstd = rsqrtf(ss / W - mu * mu + 1e-5f);
    ushort4* yr = (ushort4*)(y + (size_t)row * W);
    #pragma unroll
    for (int i = 0; i < NC; ++i) {
        int c = lane + i * 64;
        float4 t = v[i];
        float4 gg = g4[c], bb = b4[c];
        ushort4 o;
        o.x = f2bf_bits((t.x - mu) * rstd * gg.x + bb.x);
        o.y = f2bf_bits((t.y - mu) * rstd * gg.y + bb.y);
        o.z = f2bf_bits((t.z - mu) * rstd * gg.z + bb.z);
        o.w = f2bf_bits((t.w - mu) * rstd * gg.w + bb.w);
        yr[c] = o;
    }
}

// =================== stage1: 256x256-tile pipelined GEMM, 2 phases/K-tile ===================
// blocks [0,192)   : KV: xkv[8192,1920] @ WkvT[1536,1920]^T; n<768->kb, n>=768->VT
//                    XCD-aware mapping: bid%8 = XCD; each XCD's 24 blocks share
//                    4 A-panels (3.9 MB -> L2-resident) x all 6 N-panels.
// blocks [192,216) : Q:  xq[2048,768]  @ WqT[768,768]^T    -> qb
//
// Per K-tile g, TWO phases:
//   PhA: read a0,b0,b1 (16 ds_read_b128); stage A0,B0,B1(g+1); vmcnt(6)
//        [confirms A1(g) for PhB]; barrier; MFMA quadrants (0,0),(0,1).
//   PhB: read a1 (8); stage A1(g+1); vmcnt(2) [confirms A0,B0,B1(g+1) for
//        next PhA]; barrier; MFMA (1,0),(1,1)  [b0,b1 reused from registers].
// Never drains vmcnt to 0 mid-loop; every cross-wave LDS read is guarded by a
// vmcnt-before-barrier in the preceding phase.
#define VM6 asm volatile("s_waitcnt vmcnt(6)" ::: "memory")
#define VM2 asm volatile("s_waitcnt vmcnt(2)" ::: "memory")
#define VM0 asm volatile("s_waitcnt vmcnt(0)" ::: "memory")

#define STAGE_A(d, h, tau) do { \
    int _o = (aRow + (h) * 64) * Kd + (tau) * 64 + cgo; \
    __hip_bfloat16* _dp = SM + (d) * 32768 + (h) * 8192 + wido; \
    glds16(Ag + _o, _dp); \
    glds16(Ag + _o + 128 * Kd, _dp + 4096); \
} while (0)

#define STAGE_B(d, h, tau) do { \
    int _o = (bRow + (h) * 32) * Kd + (tau) * 64 + cgo; \
    __hip_bfloat16* _dp = SM + (d) * 32768 + 16384 + (h) * 8192 + wido; \
    glds16(Bg + _o, _dp); \
    glds16(Bg + _o + 128 * Kd, _dp + 4096); \
} while (0)

#define LDS_A_FRAG(dst, MH) do { \
    const __hip_bfloat16* _Ab = SM + cur * 32768 + (MH) * 8192 + aoff; \
    _Pragma("unroll") \
    for (int i = 0; i < 4; ++i) { \
        dst[i][0] = *(const bf16x8*)(_Ab + i * 1024 + c0); \
        dst[i][1] = *(const bf16x8*)(_Ab + i * 1024 + c1); \
    } \
} while (0)

#define LDS_B_FRAG(dst, NH) do { \
    const __hip_bfloat16* _Bb = SM + cur * 32768 + 16384 + (NH) * 8192 + boff; \
    _Pragma("unroll") \
    for (int j = 0; j < 2; ++j) { \
        dst[j][0] = *(const bf16x8*)(_Bb + j * 1024 + c0); \
        dst[j][1] = *(const bf16x8*)(_Bb + j * 1024 + c1); \
    } \
} while (0)

// barrier + 32 MFMA (both N-halves for row-half MH); b0,b1 read from registers
#define PHASE_MFMA(MH, af) do { \
    __builtin_amdgcn_sched_barrier(0); \
    __builtin_amdgcn_s_barrier(); \
    __builtin_amdgcn_sched_barrier(0); \
    __builtin_amdgcn_s_setprio(1); \
    _Pragma("unroll") \
    for (int i = 0; i < 4; ++i) \
        _Pragma("unroll") \
        for (int j = 0; j < 2; ++j) { \
            f32x4 _t = acc[(MH) * 4 + i][j]; \
            _t = __builtin_amdgcn_mfma_f32_16x16x32_bf16(af[i][0], b0[j][0], _t, 0, 0, 0); \
            _t = __builtin_amdgcn_mfma_f32_16x16x32_bf16(af[i][1], b0[j][1], _t, 0, 0, 0); \
            acc[(MH) * 4 + i][j] = _t; \
        } \
    _Pragma("unroll") \
    for (int i = 0; i < 4; ++i) \
        _Pragma("unroll") \
        for (int j = 0; j < 2; ++j) { \
            f32x4 _t = acc[(MH) * 4 + i][2 + j]; \
            _t = __builtin_amdgcn_mfma_f32_16x16x32_bf16(af[i][0], b1[j][0], _t, 0, 0, 0); \
            _t = __builtin_amdgcn_mfma_f32_16x16x32_bf16(af[i][1], b1[j][1], _t, 0, 0, 0); \
            acc[(MH) * 4 + i][2 + j] = _t; \
        } \
    __builtin_amdgcn_s_setprio(0); \
} while (0)

__global__ __launch_bounds__(512, 2) void stage1(const __hip_bfloat16* __restrict__ xq,
                                                 const __hip_bfloat16* __restrict__ WqT,
                                                 const float* __restrict__ bq,
                                                 __hip_bfloat16* __restrict__ qb,
                                                 const __hip_bfloat16* __restrict__ xkv,
                                                 const __hip_bfloat16* __restrict__ WkvT,
                                                 const float* __restrict__ bk,
                                                 const float* __restrict__ bv,
                                                 __hip_bfloat16* __restrict__ kb,
                                                 __hip_bfloat16* __restrict__ VT) {
    __shared__ __hip_bfloat16 SM[65536];   // 128 KiB: [buf2][ A 256x64 | B 256x64 ]
    int bid = blockIdx.x;
    int tid = threadIdx.x;
    int wid = tid >> 6, lane = tid & 63;
    int l4 = lane & 15, lq = lane >> 4;
    int wr = wid >> 2, wc = wid & 3;
    int tr = tid >> 3;                       // 0..63
    int cgo = ((tid & 7) ^ (tr & 7)) * 8;    // swizzled col offset (elems) for staging
    int wido = wid * 512;                    // wave-uniform LDS dest (elems)

    const __hip_bfloat16 *Ag, *Bg;
    int m0, n0, Kd, NT, isQ;
    if (bid < 192) {
        // XCD-aware: XCD x = bid&7 gets m-panels {4x..4x+3} x n-panels {0..5}
        int x = bid & 7, i = bid >> 3;
        m0 = (x * 4 + (i & 3)) * 256; n0 = (i >> 2) * 256;
        Ag = xkv; Bg = WkvT; Kd = COG; NT = COG / 64; isQ = 0;
    } else {
        int t = bid - 192;
        m0 = (t & 7) * 256; n0 = (t >> 3) * 256;
        Ag = xq; Bg = WqT; Kd = DINO; NT = DINO / 64; isQ = 1;
    }

    const int aRow = m0 + tr;                                  // + h*64 (+128 second glds)
    const int bRow = n0 + ((tid >> 8) << 6) + (tr & 31);       // + h*32 (+128 second glds)
    const int aoff = (wr * 64 + l4) * 64;
    const int boff = (wc * 32 + l4) * 64;
    const int c0 = ((lq) ^ (l4 & 7)) * 8;
    const int c1 = ((4 + lq) ^ (l4 & 7)) * 8;

    f32x4 acc[8][4];
    #pragma unroll
    for (int i = 0; i < 8; ++i)
        #pragma unroll
        for (int j = 0; j < 4; ++j) acc[i][j] = (f32x4){0.f, 0.f, 0.f, 0.f};

    bf16x8 a0[4][2], a1[4][2], b0[2][2], b1[2][2];

    // prologue: stage tile 0; confirm A0,B0,B1(0); A1(0) stays in flight
    STAGE_A(0, 0, 0); STAGE_B(0, 0, 0); STAGE_B(0, 1, 0); STAGE_A(0, 1, 0);
    VM2;
    __builtin_amdgcn_s_barrier();

    for (int g = 0; g < NT; ++g) {
        int cur = g & 1, nxt = cur ^ 1;
        bool s1 = (g + 1 < NT);
        // PhA: reads a0,b0,b1 ; stages A0,B0,B1(g+1) ; MFMA (0,0)+(0,1)
        LDS_A_FRAG(a0, 0);
        LDS_B_FRAG(b0, 0);
        LDS_B_FRAG(b1, 1);
        if (s1) { STAGE_A(nxt, 0, g + 1); STAGE_B(nxt, 0, g + 1); STAGE_B(nxt, 1, g + 1); VM6; }
        else VM0;
        PHASE_MFMA(0, a0);
        // PhB: reads a1 ; stages A1(g+1) ; MFMA (1,0)+(1,1)  [b0,b1 in regs]
        LDS_A_FRAG(a1, 1);
        if (s1) { STAGE_A(nxt, 1, g + 1); VM2; }
        PHASE_MFMA(1, a1);
    }

    // epilogue: C/D layout col=l4, row=lq*4+r
    if (isQ) {
        #pragma unroll
        for (int ii = 0; ii < 8; ++ii)
            #pragma unroll
            for (int jj = 0; jj < 4; ++jj) {
                int m = m0 + wr * 128 + (ii >> 2) * 64 + (ii & 3) * 16 + lq * 4;
                int n = n0 + wc * 64 + (jj >> 1) * 32 + (jj & 1) * 16 + l4;
                float bb = bq[n];
                #pragma unroll
                for (int r = 0; r < 4; ++r)
                    qb[(size_t)(m + r) * DINO + n] = __float2bfloat16(acc[ii][jj][r] + bb);
            }
    } else if (n0 < 768) {
        #pragma unroll
        for (int ii = 0; ii < 8; ++ii)
            #pragma unroll
            for (int jj = 0; jj < 4; ++jj) {
                int m = m0 + wr * 128 + (ii >> 2) * 64 + (ii & 3) * 16 + lq * 4;
                int n = n0 + wc * 64 + (jj >> 1) * 32 + (jj & 1) * 16 + l4;
                float bb = bk[n];
                #pragma unroll
                for (int r = 0; r < 4; ++r)
                    kb[(size_t)(m + r) * DINO + n] = __float2bfloat16(acc[ii][jj][r] + bb);
            }
    } else {
        #pragma unroll
        for (int ii = 0; ii < 8; ++ii)
            #pragma unroll
            for (int jj = 0; jj < 4; ++jj) {
                int m = m0 + wr * 128 + (ii >> 2) * 64 + (ii & 3) * 16 + lq * 4;
                int nv = n0 - 768 + wc * 64 + (jj >> 1) * 32 + (jj & 1) * 16 + l4;
                float bb = bv[nv];
                #pragma unroll
                for (int r = 0; r < 4; ++r) {
                    int mm = m + r;
                    VT[((size_t)((mm >> 12) * 768 + nv)) * TKV + (mm & 4095)] =
                        __float2bfloat16(acc[ii][jj][r] + bb);
                }
            }
    }
}

// =================== O projection: 64x64 tiles (C^T epilogue -> NCHW fp32) ===================
__global__ __launch_bounds__(256) void gemm_o(const __hip_bfloat16* __restrict__ A,
                                              const __hip_bfloat16* __restrict__ Bt,
                                              const float* __restrict__ bias,
                                              float* __restrict__ out) {
    const int K = DINO;
    __shared__ __hip_bfloat16 As[64 * 64];
    __shared__ __hip_bfloat16 Bs[64 * 64];
    int m0 = blockIdx.x * 64, n0 = blockIdx.y * 64;
    int tid = threadIdx.x, w = tid >> 6, lane = tid & 63;
    int l4 = lane & 15, lq = lane >> 4;
    int mq = (w & 1) * 32, nq = (w >> 1) * 32;
    f32x4 acc[2][2];
    #pragma unroll
    for (int i = 0; i < 2; ++i)
        #pragma unroll
        for (int j = 0; j < 2; ++j) acc[i][j] = (f32x4){0.f, 0.f, 0.f, 0.f};

    int rr = tid >> 3;
    int gc = (tid & 7) ^ (rr & 7);
    const __hip_bfloat16* ag = A  + (size_t)(m0 + rr) * K + gc * 8;
    const __hip_bfloat16* bg = Bt + (size_t)(n0 + rr) * K + gc * 8;
    __hip_bfloat16* asl = As + (w * 8) * 64;
    __hip_bfloat16* bsl = Bs + (w * 8) * 64;
    int sws = l4 & 7;

    for (int k0 = 0; k0 < K; k0 += 64) {
        __syncthreads();
        #pragma unroll
        for (int g = 0; g < 2; ++g) {
            glds16(ag + (size_t)(g * 32) * K + k0, asl + g * 32 * 64);
            glds16(bg + (size_t)(g * 32) * K + k0, bsl + g * 32 * 64);
        }
        __syncthreads();
        #pragma unroll
        for (int h = 0; h < 2; ++h) {
            bf16x8 a[2], b[2];
            #pragma unroll
            for (int i = 0; i < 2; ++i)
                a[i] = *(const bf16x8*)(As + (mq + 16 * i + l4) * 64 + (((h * 4 + lq) ^ sws) * 8));
            #pragma unroll
            for (int j = 0; j < 2; ++j)
                b[j] = *(const bf16x8*)(Bs + (nq + 16 * j + l4) * 64 + (((h * 4 + lq) ^ sws) * 8));
            #pragma unroll
            for (int i = 0; i < 2; ++i)
                #pragma unroll
                for (int j = 0; j < 2; ++j)
                    acc[i][j] = __builtin_amdgcn_mfma_f32_16x16x32_bf16(b[j], a[i], acc[i][j], 0, 0, 0);
        }
    }
    #pragma unroll
    for (int i = 0; i < 2; ++i)
        #pragma unroll
        for (int j = 0; j < 2; ++j)
            #pragma unroll
            for (int r = 0; r < 4; ++r) {
                int n = n0 + nq + 16 * j + lq * 4 + r;
                int m = m0 + mq + 16 * i + l4;
                int b = m >> 10, hw = m & 1023;
                out[((size_t)b * DINO + n) * HWl + hw] = acc[i][j][r] + bias[n];
            }
}

// =================== flash attention: 128-q tile, K/V double-buffered glds ===================
__global__ __launch_bounds__(256) void attn4(const __hip_bfloat16* __restrict__ qb,
                                             const __hip_bfloat16* __restrict__ kb,
                                             const __hip_bfloat16* __restrict__ VT,
                                             const float* __restrict__ tw,
                                             __hip_bfloat16* __restrict__ Opart,
                                             float* __restrict__ lpart) {
    int bid = blockIdx.x;
    int g = bid % 96, qc = bid / 96;
    int s = g & 3, bh = g >> 2;
    int head = bh % NHh, b = bh / NHh;
    int tid = threadIdx.x, w = tid >> 6, lane = tid & 63;
    int l4 = lane & 15, lq = lane >> 4;

    __shared__ __hip_bfloat16 Ks[2 * 64 * 64];
    __shared__ __hip_bfloat16 Vs[2 * 64 * 64];
    __shared__ __hip_bfloat16 Ps[4 * 32 * 64];

    const __hip_bfloat16* qbase = qb + (size_t)(b * HWl + qc * 128 + w * 32 + l4) * DINO + head * 64;
    bf16x8 qA0 = *(const bf16x8*)(qbase + lq * 8);
    bf16x8 qA1 = *(const bf16x8*)(qbase + 32 + lq * 8);
    const __hip_bfloat16* qbase2 = qbase + (size_t)16 * DINO;
    bf16x8 qB0 = *(const bf16x8*)(qbase2 + lq * 8);
    bf16x8 qB1 = *(const bf16x8*)(qbase2 + 32 + lq * 8);

    float c = tw[s] * 0.125f * 1.44269504f;
    float l_iA = 0.f, l_iB = 0.f;
    f32x4 oA[4], oB[4];
    #pragma unroll
    for (int j = 0; j < 4; ++j) { oA[j] = (f32x4){0.f,0.f,0.f,0.f}; oB[j] = (f32x4){0.f,0.f,0.f,0.f}; }

    int rowA = w * 16 + (lane >> 3);
    int cg = (lane & 7) ^ ((lane >> 3) & 7);
    const __hip_bfloat16* kg0 = kb + (size_t)(b * TKV + s * 1024 + rowA) * DINO + head * 64 + cg * 8;
    const __hip_bfloat16* kg1 = kg0 + (size_t)8 * DINO;
    const __hip_bfloat16* vg0 = VT + (size_t)(b * 768 + head * 64 + rowA) * TKV + s * 1024 + cg * 8;
    const __hip_bfloat16* vg1 = vg0 + (size_t)8 * TKV;
    int klo0 = (w * 2 + 0) * 512, klo1 = (w * 2 + 1) * 512;

    int sw0 = (lq ^ (l4 & 7)) * 8;
    int sw1 = ((4 + lq) ^ (l4 & 7)) * 8;
    __hip_bfloat16* PsA = Ps + w * 2048 + l4 * 64;
    __hip_bfloat16* PsB = Ps + w * 2048 + (16 + l4) * 64;

    // prologue: stage tile 0 into buffer 0
    glds16(kg0, Ks + klo0);
    glds16(kg1, Ks + klo1);
    glds16(vg0, Vs + klo0);
    glds16(vg1, Vs + klo1);

    for (int kt = 0; kt < 16; ++kt) {
        int cur = (kt & 1) * 4096;
        __syncthreads();   // drains pending glds (incl. prefetch of this tile)
        if (kt < 15) {
            int nxt = cur ^ 4096;
            glds16(kg0 + (size_t)(kt + 1) * 64 * DINO, Ks + nxt + klo0);
            glds16(kg1 + (size_t)(kt + 1) * 64 * DINO, Ks + nxt + klo1);
            glds16(vg0 + (kt + 1) * 64, Vs + nxt + klo0);
            glds16(vg1 + (kt + 1) * 64, Vs + nxt + klo1);
        }
        const __hip_bfloat16* Kc = Ks + cur;
        const __hip_bfloat16* Vc = Vs + cur;

        f32x4 stA[4], stB[4];
        #pragma unroll
        for (int j = 0; j < 4; ++j) {
            const __hip_bfloat16* kr = Kc + (16 * j + l4) * 64;
            bf16x8 kf0 = *(const bf16x8*)(kr + sw0);
            bf16x8 kf1 = *(const bf16x8*)(kr + sw1);
            f32x4 a = (f32x4){0.f,0.f,0.f,0.f};
            a = __builtin_amdgcn_mfma_f32_16x16x32_bf16(kf0, qA0, a, 0, 0, 0);
            a = __builtin_amdgcn_mfma_f32_16x16x32_bf16(kf1, qA1, a, 0, 0, 0);
            stA[j] = a;
            f32x4 bb = (f32x4){0.f,0.f,0.f,0.f};
            bb = __builtin_amdgcn_mfma_f32_16x16x32_bf16(kf0, qB0, bb, 0, 0, 0);
            bb = __builtin_amdgcn_mfma_f32_16x16x32_bf16(kf1, qB1, bb, 0, 0, 0);
            stB[j] = bb;
        }

        float lsA = 0.f, lsB = 0.f;
        #pragma unroll
        for (int j = 0; j < 4; ++j)
            #pragma unroll
            for (int r = 0; r < 4; ++r) {
                float eA = exp2f(stA[j][r] * c);
                float eB = exp2f(stB[j][r] * c);
                stA[j][r] = eA; lsA += eA;
                stB[j][r] = eB; lsB += eB;
            }
        lsA += __shfl_xor(lsA, 16); lsA += __shfl_xor(lsA, 32);
        lsB += __shfl_xor(lsB, 16); lsB += __shfl_xor(lsB, 32);
        l_iA += lsA; l_iB += lsB;

        #pragma unroll
        for (int j = 0; j < 4; ++j) {
            int off = (((2 * j + (lq >> 1)) ^ (l4 & 7)) << 3) + (lq & 1) * 4;
            ushort4 pA, pB;
            pA.x = f2bf_bits(stA[j][0]); pA.y = f2bf_bits(stA[j][1]);
            pA.z = f2bf_bits(stA[j][2]); pA.w = f2bf_bits(stA[j][3]);
            pB.x = f2bf_bits(stB[j][0]); pB.y = f2bf_bits(stB[j][1]);
            pB.z = f2bf_bits(stB[j][2]); pB.w = f2bf_bits(stB[j][3]);
            *(ushort4*)&PsA[off] = pA;
            *(ushort4*)&PsB[off] = pB;
        }
        bf16x8 paA0 = *(const bf16x8*)(PsA + sw0);
        bf16x8 paA1 = *(const bf16x8*)(PsA + sw1);
        bf16x8 paB0 = *(const bf16x8*)(PsB + sw0);
        bf16x8 paB1 = *(const bf16x8*)(PsB + sw1);

        #pragma unroll
        for (int j = 0; j < 4; ++j) {
            const __hip_bfloat16* vr = Vc + (16 * j + l4) * 64;
            bf16x8 vf0 = *(const bf16x8*)(vr + sw0);
            bf16x8 vf1 = *(const bf16x8*)(vr + sw1);
            oA[j] = __builtin_amdgcn_mfma_f32_16x16x32_bf16(paA0, vf0, oA[j], 0, 0, 0);
            oA[j] = __builtin_amdgcn_mfma_f32_16x16x32_bf16(paA1, vf1, oA[j], 0, 0, 0);
            oB[j] = __builtin_amdgcn_mfma_f32_16x16x32_bf16(paB0, vf0, oB[j], 0, 0, 0);
            oB[j] = __builtin_amdgcn_mfma_f32_16x16x32_bf16(paB1, vf1, oB[j], 0, 0, 0);
        }
    }

    size_t rb = (size_t)s * ROWS_PER_SPLIT + (size_t)(b * NHh + head) * HWl + qc * 128 + w * 32;
    #pragma unroll
    for (int j = 0; j < 4; ++j)
        #pragma unroll
        for (int r = 0; r < 4; ++r) {
            Opart[(rb + lq * 4 + r) * 64 + j * 16 + l4]      = __float2bfloat16(oA[j][r]);
            Opart[(rb + 16 + lq * 4 + r) * 64 + j * 16 + l4] = __float2bfloat16(oB[j][r]);
        }
    if (lq == 0) {
        lpart[rb + l4]      = l_iA;
        lpart[rb + 16 + l4] = l_iB;
    }
}

// =================== combine split partials ===================
__global__ void combine(const __hip_bfloat16* __restrict__ Opart, const float* __restrict__ lpart,
                        __hip_bfloat16* __restrict__ attn) {
    int p = blockIdx.x * 4 + (threadIdx.x >> 6);
    int d = threadIdx.x & 63;
    float L = 0.f, O = 0.f;
    #pragma unroll
    for (int s = 0; s < NSPL; ++s) {
        L += lpart[(size_t)s * ROWS_PER_SPLIT + p];
        O += __bfloat162float(Opart[((size_t)s * ROWS_PER_SPLIT + p) * 64 + d]);
    }
    float res = O / L;
    int q = p & 1023;
    int bh = p >> 10;
    int head = bh % NHh, b = bh / NHh;
    attn[((size_t)(b * HWl + q)) * DINO + head * 64 + d] = __float2bfloat16(res);
}

// =================== launch ===================
extern "C" void kernel_launch(void* const* d_in, const int* in_sizes, int n_in,
                              void* d_out, int out_size, void* d_ws, size_t ws_size,
                              hipStream_t stream) {
    (void)in_sizes; (void)n_in; (void)out_size; (void)ws_size;
    const float* dino = (const float*)d_in[0];
    const float* cog  = (const float*)d_in[1];
    const float* tw   = (const float*)d_in[2];
    const float* Wq   = (const float*)d_in[3];
    const float* bq   = (const float*)d_in[4];
    const float* Wk   = (const float*)d_in[5];
    const float* bk   = (const float*)d_in[6];
    const float* Wv   = (const float*)d_in[7];
    const float* bv   = (const float*)d_in[8];
    const float* Wo   = (const float*)d_in[9];
    const float* bo   = (const float*)d_in[10];
    const float* gq   = (const float*)d_in[11];
    const float* Bq   = (const float*)d_in[12];
    const float* gkv  = (const float*)d_in[13];
    const float* Bkv  = (const float*)d_in[14];

    char* p = (char*)d_ws;
    float* xqT = (float*)p;                    p += (size_t)MQ * DINO * 4;
    __hip_bfloat16* xq = (__hip_bfloat16*)p;   p += (size_t)MQ * DINO * 2;
    char* alias = p;                           p += (size_t)MKV * COG * 2;   // xkv | Opart+lpart
    __hip_bfloat16* xkv = (__hip_bfloat16*)alias;
    __hip_bfloat16* WqT  = (__hip_bfloat16*)p; p += (size_t)DINO * DINO * 2;
    __hip_bfloat16* WkvT = (__hip_bfloat16*)p; p += (size_t)1536 * COG * 2;
    __hip_bfloat16* WoT  = (__hip_bfloat16*)p; p += (size_t)DINO * DINO * 2;
    __hip_bfloat16* qb   = (__hip_bfloat16*)p; p += (size_t)MQ  * DINO * 2;
    __hip_bfloat16* kb   = (__hip_bfloat16*)p; p += (size_t)MKV * DINO * 2;
    __hip_bfloat16* VT   = (__hip_bfloat16*)p; p += (size_t)MKV * DINO * 2;
    __hip_bfloat16* attnb = (__hip_bfloat16*)p; p += (size_t)MQ * DINO * 2;
    __hip_bfloat16* Opart = (__hip_bfloat16*)alias;
    float* lpart = (float*)(alias + (size_t)NSPL * ROWS_PER_SPLIT * 64 * 2);

    prep1<<<8192, 256, 0, stream>>>(dino, cog, gkv, Bkv,
                                    Wq, Wk, Wv, Wo, xqT, xkv, WqT, WkvT, WoT);
    prep2<<<MQ / 4, 256, 0, stream>>>(xqT, gq, Bq, xq);
    stage1<<<216, 512, 0, stream>>>(xq, WqT, bq, qb, xkv, WkvT, bk, bv, kb, VT);
    attn4<<<BB * NHh * 8 * NSPL, 256, 0, stream>>>(qb, kb, VT, tw, Opart, lpart);
    combine<<<ROWS_PER_SPLIT / 4, 256, 0, stream>>>(Opart, lpart, attnb);
    gemm_o<<<dim3(32, 12), 256, 0, stream>>>(attnb, WoT, bo, (float*)d_out);
}